// Round 1
// baseline (429.965 us; speedup 1.0000x reference)
//
#include <hip/hip_runtime.h>
#include <stdint.h>

// SO3Conv: out[b,g,off_l + v*d + m] = (1/sqrt(64*d)) * sum_{f,u} x[b,f,off_l+u*d+m] * psi[f,g,off_l+u*d+v]
// psi[f,g,i] = sum_n D[n,i] w[f,g,n] / 8
//
// Mapped per l to GEMM: C[(b,m),(g,v)] = A[(b,m),(u,f)] * B[(u,f),(g,v)]
//   A: pre-transposed x, bf16, row-major [M=1024d][K=64d], k = u*64+f
//   B: psi with norms folded, bf16, stored B-operand-wise Bt[n][k], n=(g*d+v), rows padded to 128-mult with zeros
// Workspace: A buffers then B buffers, ~63.8 MB total.

typedef __bf16 bf16x8 __attribute__((ext_vector_type(8)));
typedef float floatx4 __attribute__((ext_vector_type(4)));

#define XROW 29120   // 64*455

__device__ __forceinline__ unsigned short f2bf(float f) {
  union { float f; unsigned int u; } c; c.f = f;
  unsigned int u = c.u;
  return (unsigned short)((u + 0x7FFFu + ((u >> 16) & 1u)) >> 16);
}

__host__ __device__ constexpr int d_of(int L) { return 2 * L + 1; }
__host__ __device__ constexpr int off_of(int L) { int s = 0; for (int i = 0; i < L; ++i) s += d_of(i) * d_of(i); return s; }
// ushort-element offsets into workspace
__host__ __device__ constexpr size_t a_off(int L) { size_t s = 0; for (int i = 0; i < L; ++i) s += (size_t)65536 * d_of(i) * d_of(i); return s; }
__host__ __device__ constexpr size_t b_off(int L) { size_t s = a_off(7); for (int i = 0; i < L; ++i) s += (size_t)4096 * d_of(i) * (d_of(i) + 1); return s; }

// ---------------- Kernel 1: build B = psi (bf16, B-operand layout, norms folded) ----------------
__global__ __launch_bounds__(256) void build_B(const float* __restrict__ D, const float* __restrict__ w,
                                               unsigned short* __restrict__ ws) {
  __shared__ float wg[64 * 65];    // wg[n'][f], row stride 65 (transpose pad)
  __shared__ float Dl[64 * 169];   // Dl[n'][r], row stride d2
  const int g = blockIdx.x;   // 0..63
  const int l = blockIdx.y;   // 0..6
  const int d = 2 * l + 1, d2 = d * d, K = 64 * d;
  int off = 0; size_t boff = a_off(7);
  for (int i = 0; i < l; ++i) { int dd = 2 * i + 1; off += dd * dd; boff += (size_t)4096 * dd * (dd + 1); }
  unsigned short* B = ws + boff;
  const int tid = threadIdx.x;

  // stage w[:, g, :] transposed: wg[n][f] = w[f,g,n]   (read coalesced, write stride 65 -> conflict-free)
  for (int t = tid; t < 4096; t += 256) {
    int n = t & 63, f = t >> 6;
    wg[n * 65 + f] = w[f * 4096 + g * 64 + n];
  }
  // stage D columns: Dl[n][r] = D[n, off + r],  r = u*d+v
  for (int t = tid; t < 64 * d2; t += 256) {
    int r = t % d2, n = t / d2;
    Dl[n * d2 + r] = D[n * 455 + off + r];
  }
  __syncthreads();

  const float sl = 1.0f / (64.0f * sqrtf((float)d));
  for (int j = tid; j < 64 * d2; j += 256) {
    int f = j & 63, r = j >> 6;          // wave: f varies, r uniform -> Dl broadcast, wg stride-1
    int u = r / d, v = r - u * d;
    float acc = 0.f;
#pragma unroll 8
    for (int n = 0; n < 64; ++n) acc += wg[n * 65 + f] * Dl[n * d2 + r];
    int nn = g * d + v, k = u * 64 + f;
    B[(size_t)nn * K + k] = f2bf(acc * sl);
  }
  // zero one pad row per block (64 pad rows total per l)
  {
    int nn = 64 * d + g;
    for (int k = tid; k < K; k += 256) B[(size_t)nn * K + k] = 0;
  }
}

// ---------------- Kernel 2: transpose x -> A (bf16) ----------------
__global__ __launch_bounds__(256) void transpose_x(const float* __restrict__ x, unsigned short* __restrict__ ws) {
  __shared__ float xs[64 * 169];  // xs[f][r] for current l
  const int b = blockIdx.x, tid = threadIdx.x;
  const float* xb = x + (size_t)b * XROW;
  size_t aoff = 0;
  int off = 0;
#pragma unroll
  for (int l = 0; l < 7; ++l) {
    const int d = 2 * l + 1, d2 = d * d;
    const int n1 = 64 * d2;
    for (int t = tid; t < n1; t += 256) xs[t] = xb[(t / d2) * 455 + off + (t % d2)];
    __syncthreads();
    unsigned short* A = ws + aoff + (size_t)b * n1;
    for (int t = tid; t < n1; t += 256) {
      int f = t & 63, s = t >> 6;
      int u = s % d, m = s / d;
      A[t] = f2bf(xs[f * d2 + u * d + m]);   // lane stride d2 (odd) -> conflict-free
    }
    __syncthreads();
    off += d2; aoff += (size_t)1024 * n1;
  }
}

// ---------------- Kernel 3: fused all-l MFMA GEMM ----------------
__device__ __forceinline__ void async_copy16(const void* gp, void* lp) {
  __builtin_amdgcn_global_load_lds((__attribute__((address_space(1))) void*)gp,
                                   (__attribute__((address_space(3))) void*)lp, 16, 0, 0);
}

template <int L>
__device__ __forceinline__ void gemm_body(int local, const unsigned short* __restrict__ ws,
                                          float* __restrict__ out,
                                          unsigned short* As, unsigned short* Bs) {
  constexpr int d = 2 * L + 1;
  constexpr int K = 64 * d;
  constexpr int NT = (d + 1) / 2;          // N-tiles of 128 (N padded to 64*(d+1))
  constexpr int OFF = off_of(L);
  const unsigned short* A = ws + a_off(L);
  const unsigned short* B = ws + b_off(L);
  const int mt = local / NT, nt = local % NT;
  const int tid = threadIdx.x;
  const int w = tid >> 6, ln = tid & 63;
  const int wm = w >> 1, wn = w & 1;
  const int q = ln >> 4, r16 = ln & 15;

  // staging pointers: 4 issues x 256 threads x 16B = 16KB (A 8KB + B 8KB)
  const unsigned short* gp[4];
  unsigned short* ldst[4];
#pragma unroll
  for (int i = 0; i < 4; ++i) {
    int c = i * 256 + tid;
    if (i < 2) {
      gp[i] = A + (size_t)(mt * 128 + (c >> 2)) * K + (c & 3) * 8;
      ldst[i] = As + (i * 256 + w * 64) * 8;
    } else {
      int c2 = c - 512;
      gp[i] = B + (size_t)(nt * 128 + (c2 >> 2)) * K + (c2 & 3) * 8;
      ldst[i] = Bs + ((i - 2) * 256 + w * 64) * 8;
    }
  }

  const int aoffs0 = (wm * 64 + r16) * 32 + q * 8;  // ushort units into As[128][32]
  const int boffs0 = (wn * 64 + r16) * 32 + q * 8;

  floatx4 acc[4][4] = {};

  for (int kt = 0; kt < 2 * d; ++kt) {
    __syncthreads();
#pragma unroll
    for (int i = 0; i < 4; ++i) async_copy16(gp[i], ldst[i]);
    __syncthreads();   // compiler emits s_waitcnt vmcnt(0) before s_barrier
    bf16x8 af[4], bfr[4];
#pragma unroll
    for (int mi = 0; mi < 4; ++mi) af[mi] = *(const bf16x8*)(As + aoffs0 + mi * 512);
#pragma unroll
    for (int ni = 0; ni < 4; ++ni) bfr[ni] = *(const bf16x8*)(Bs + boffs0 + ni * 512);
#pragma unroll
    for (int mi = 0; mi < 4; ++mi)
#pragma unroll
      for (int ni = 0; ni < 4; ++ni)
        acc[mi][ni] = __builtin_amdgcn_mfma_f32_16x16x32_bf16(af[mi], bfr[ni], acc[mi][ni], 0, 0, 0);
#pragma unroll
    for (int i = 0; i < 4; ++i) gp[i] += 32;
  }

  // epilogue: D[row=q*4+reg (M=(b,m)), col=r16 (N=(g,v))]
#pragma unroll
  for (int ni = 0; ni < 4; ++ni) {
    int Cc = nt * 128 + wn * 64 + ni * 16 + r16;
    if (Cc < 64 * d) {
      int g = Cc / d, v = Cc - (Cc / d) * d;
#pragma unroll
      for (int mi = 0; mi < 4; ++mi) {
        int R0 = mt * 128 + wm * 64 + mi * 16 + q * 4;
#pragma unroll
        for (int reg = 0; reg < 4; ++reg) {
          int R = R0 + reg;
          int bb = R / d, m = R - (R / d) * d;
          out[(size_t)bb * XROW + g * 455 + OFF + v * d + m] = acc[mi][ni][reg];
        }
      }
    }
  }
}

__global__ __launch_bounds__(256) void gemm_all(const unsigned short* __restrict__ ws, float* __restrict__ out) {
  __shared__ alignas(16) unsigned short As[128 * 32];
  __shared__ alignas(16) unsigned short Bs[128 * 32];
  // blocks per l: 4d(d+1) = {8,48,120,224,360,528,728}; cum {8,56,176,400,760,1288,2016}
  int b0 = 2015 - (int)blockIdx.x;   // longest-l blocks dispatch first
  if      (b0 <    8) gemm_body<0>(b0,        ws, out, As, Bs);
  else if (b0 <   56) gemm_body<1>(b0 -    8, ws, out, As, Bs);
  else if (b0 <  176) gemm_body<2>(b0 -   56, ws, out, As, Bs);
  else if (b0 <  400) gemm_body<3>(b0 -  176, ws, out, As, Bs);
  else if (b0 <  760) gemm_body<4>(b0 -  400, ws, out, As, Bs);
  else if (b0 < 1288) gemm_body<5>(b0 -  760, ws, out, As, Bs);
  else                gemm_body<6>(b0 - 1288, ws, out, As, Bs);
}

extern "C" void kernel_launch(void* const* d_in, const int* in_sizes, int n_in,
                              void* d_out, int out_size, void* d_ws, size_t ws_size,
                              hipStream_t stream) {
  const float* x = (const float*)d_in[0];
  const float* D = (const float*)d_in[1];
  const float* w = (const float*)d_in[2];
  float* out = (float*)d_out;
  unsigned short* ws = (unsigned short*)d_ws;   // needs ~63.8 MB

  hipLaunchKernelGGL(build_B, dim3(64, 7), dim3(256), 0, stream, D, w, ws);
  hipLaunchKernelGGL(transpose_x, dim3(1024), dim3(256), 0, stream, x, ws);
  hipLaunchKernelGGL(gemm_all, dim3(2016), dim3(256), 0, stream, ws, out);
}

// Round 2
// 367.175 us; speedup vs baseline: 1.1710x; 1.1710x over previous
//
#include <hip/hip_runtime.h>
#include <stdint.h>

// SO3Conv mapped per l to GEMM: C[(b,m),(g,v)] = A[(b,m),(u,f)] * B[(u,f),(g,v)]
//   A: pre-transposed x, bf16, row-major [M=1024d][K=64d], k = u*64+f
//   B: psi with both norms folded, bf16, B-operand layout Bt[n=(g*d+v)][k], rows padded to 128-mult with 0
// Workspace: A buffers then B buffers, ~63.8 MB.

typedef __bf16 bf16x8 __attribute__((ext_vector_type(8)));
typedef float floatx4 __attribute__((ext_vector_type(4)));

#define XROW 29120   // 64*455

__device__ __forceinline__ unsigned short f2bf(float f) {
  union { float f; unsigned int u; } c; c.f = f;
  unsigned int u = c.u;
  return (unsigned short)((u + 0x7FFFu + ((u >> 16) & 1u)) >> 16);
}
__device__ __forceinline__ unsigned int pack2(float a, float b) {
  return (unsigned int)f2bf(a) | ((unsigned int)f2bf(b) << 16);
}

__host__ __device__ constexpr int d_of(int L) { return 2 * L + 1; }
__host__ __device__ constexpr int off_of(int L) { int s = 0; for (int i = 0; i < L; ++i) s += d_of(i) * d_of(i); return s; }
__host__ __device__ constexpr size_t a_off(int L) { size_t s = 0; for (int i = 0; i < L; ++i) s += (size_t)65536 * d_of(i) * d_of(i); return s; }
__host__ __device__ constexpr size_t b_off(int L) { size_t s = a_off(7); for (int i = 0; i < L; ++i) s += (size_t)4096 * d_of(i) * (d_of(i) + 1); return s; }

// ---------------- Kernel 1 (fused): build B (blocks 0..447) + transpose x (blocks 448..1471) ----------------
__global__ __launch_bounds__(256) void prep(const float* __restrict__ x, const float* __restrict__ Dm,
                                            const float* __restrict__ w, unsigned short* __restrict__ ws) {
  __shared__ __align__(16) float smem[64 * 68 + 64 * 172];   // 60 KB: build uses both halves, transpose first 43.3KB
  const int tid = threadIdx.x;
  const int bid = blockIdx.x;

  if (bid < 448) {
    // ---- build B: psi[f,g,r] = sum_n w[f,g,n] D[n,off+r], norms folded, 4x4 register tiling ----
    float* wg = smem;              // [64][68]: wg[n][f]
    float* Dl = smem + 64 * 68;    // [64][172]: Dl[n][r], zero-padded to r<172
    const int g = bid & 63, l = bid >> 6;
    const int d = 2 * l + 1, d2 = d * d, K = 64 * d;
    int off = 0; size_t boff = a_off(7);
    for (int i = 0; i < l; ++i) { int dd = 2 * i + 1; off += dd * dd; boff += (size_t)4096 * dd * (dd + 1); }
    unsigned short* B = ws + boff;

    for (int t = tid; t < 4096; t += 256) {
      int n = t & 63, f = t >> 6;
      wg[n * 68 + f] = w[(size_t)f * 4096 + g * 64 + n];
    }
    for (int t = tid; t < 64 * 172; t += 256) {
      int n = t / 172, r = t - n * 172;
      Dl[t] = (r < d2) ? Dm[n * 455 + off + r] : 0.f;
    }
    __syncthreads();

    const float sl = 1.0f / (64.0f * sqrtf((float)d));
    const int RT = (d2 + 3) >> 2;
    for (int tt = tid; tt < 16 * RT; tt += 256) {
      const int ft = tt & 15, rt = tt >> 4;
      float acc[4][4] = {};
      for (int n = 0; n < 64; ++n) {
        floatx4 wv = *(const floatx4*)(wg + n * 68 + ft * 4);
        floatx4 dv = *(const floatx4*)(Dl + n * 172 + rt * 4);
#pragma unroll
        for (int a = 0; a < 4; ++a)
#pragma unroll
          for (int b2 = 0; b2 < 4; ++b2) acc[a][b2] += wv[a] * dv[b2];
      }
#pragma unroll
      for (int b2 = 0; b2 < 4; ++b2) {
        int r = rt * 4 + b2;
        if (r < d2) {
          int u = r / d, v = r - u * d;
          size_t base = (size_t)(g * d + v) * K + u * 64 + ft * 4;
#pragma unroll
          for (int a = 0; a < 4; ++a) B[base + a] = f2bf(acc[a][b2] * sl);
        }
      }
    }
    { // zero one pad row per g (rows 64d..64d+63 across the 64 g-blocks)
      int nn = 64 * d + g;
      for (int k = tid; k < K; k += 256) B[(size_t)nn * K + k] = 0;
    }
  } else {
    // ---- transpose x -> A (bf16, pair-packed 4B stores) ----
    float* xs = smem;
    const int b = bid - 448;
    const float* xb = x + (size_t)b * XROW;
    size_t aoff = 0;

    // phase A: l0..l4 (cols 0..165)
    for (int t = tid; t < 64 * 165; t += 256) { int f = t / 165, c = t - f * 165; xs[t] = xb[(size_t)f * 455 + c]; }
    __syncthreads();
    int off = 0;
#pragma unroll
    for (int l = 0; l < 5; ++l) {
      const int d = 2 * l + 1, d2 = d * d, n1 = 64 * d2;
      unsigned int* A = (unsigned int*)(ws + aoff + (size_t)b * n1);
      for (int t = tid; t < (n1 >> 1); t += 256) {
        int f2 = t & 31, s = t >> 5;
        int u = s % d, m = s / d;
        int c = off + u * d + m;
        A[t] = pack2(xs[(2 * f2) * 165 + c], xs[(2 * f2 + 1) * 165 + c]);
      }
      off += d2; aoff += (size_t)1024 * n1;
    }
    __syncthreads();
    // phase B: l5 (cols 165..286)
    for (int t = tid; t < 64 * 121; t += 256) { int f = t / 121, c = t - f * 121; xs[t] = xb[(size_t)f * 455 + 165 + c]; }
    __syncthreads();
    {
      const int n1 = 64 * 121;
      unsigned int* A = (unsigned int*)(ws + aoff + (size_t)b * n1);
      for (int t = tid; t < (n1 >> 1); t += 256) {
        int f2 = t & 31, s = t >> 5;
        int u = s % 11, m = s / 11;
        int c = u * 11 + m;
        A[t] = pack2(xs[(2 * f2) * 121 + c], xs[(2 * f2 + 1) * 121 + c]);
      }
      aoff += (size_t)1024 * n1;
    }
    __syncthreads();
    // phase C: l6 (cols 286..455)
    for (int t = tid; t < 64 * 169; t += 256) { int f = t / 169, c = t - f * 169; xs[t] = xb[(size_t)f * 455 + 286 + c]; }
    __syncthreads();
    {
      const int n1 = 64 * 169;
      unsigned int* A = (unsigned int*)(ws + aoff + (size_t)b * n1);
      for (int t = tid; t < (n1 >> 1); t += 256) {
        int f2 = t & 31, s = t >> 5;
        int u = s % 13, m = s / 13;
        int c = u * 13 + m;
        A[t] = pack2(xs[(2 * f2) * 169 + c], xs[(2 * f2 + 1) * 169 + c]);
      }
    }
  }
}

// ---------------- Kernel 2: fused all-l MFMA GEMM with XCD-grouped A-tile reuse ----------------
__device__ __forceinline__ void async_copy16(const void* gp, void* lp) {
  __builtin_amdgcn_global_load_lds((__attribute__((address_space(1))) void*)gp,
                                   (__attribute__((address_space(3))) void*)lp, 16, 0, 0);
}

template <int L>
__device__ __forceinline__ void gemm_body(int local, const unsigned short* __restrict__ ws,
                                          float* __restrict__ out,
                                          unsigned short* As, unsigned short* Bs) {
  constexpr int d = 2 * L + 1;
  constexpr int K = 64 * d;
  constexpr int NT = (d + 1) / 2;          // N-tiles of 128 (N padded to 64*(d+1)); M-tiles = 8d
  constexpr int OFF = off_of(L);
  const unsigned short* A = ws + a_off(L);
  const unsigned short* B = ws + b_off(L);
  // XCD swizzle: all NT blocks sharing an A M-tile land on one XCD (consecutive bid -> XCD round-robin).
  // local = x8 + 8*(mtHi*NT + nt), mt = mtHi*8 + x8;  blocks_l/8 = d*NT, M-tiles/8 = d (exact).
  const int x8 = local & 7, tt = local >> 3;
  const int mt = (tt / NT) * 8 + x8;
  const int nt = tt % NT;
  const int tid = threadIdx.x;
  const int w = tid >> 6, ln = tid & 63;
  const int wm = w >> 1, wn = w & 1;
  const int q = ln >> 4, r16 = ln & 15;

  const unsigned short* gp[4];
  unsigned short* ldst[4];
#pragma unroll
  for (int i = 0; i < 4; ++i) {
    int c = i * 256 + tid;
    if (i < 2) {
      gp[i] = A + (size_t)(mt * 128 + (c >> 2)) * K + (c & 3) * 8;
      ldst[i] = As + (i * 256 + w * 64) * 8;
    } else {
      int c2 = c - 512;
      gp[i] = B + (size_t)(nt * 128 + (c2 >> 2)) * K + (c2 & 3) * 8;
      ldst[i] = Bs + ((i - 2) * 256 + w * 64) * 8;
    }
  }

  const int aoffs0 = (wm * 64 + r16) * 32 + q * 8;
  const int boffs0 = (wn * 64 + r16) * 32 + q * 8;

  floatx4 acc[4][4] = {};

  for (int kt = 0; kt < 2 * d; ++kt) {
    __syncthreads();
#pragma unroll
    for (int i = 0; i < 4; ++i) async_copy16(gp[i], ldst[i]);
    __syncthreads();
    bf16x8 af[4], bfr[4];
#pragma unroll
    for (int mi = 0; mi < 4; ++mi) af[mi] = *(const bf16x8*)(As + aoffs0 + mi * 512);
#pragma unroll
    for (int ni = 0; ni < 4; ++ni) bfr[ni] = *(const bf16x8*)(Bs + boffs0 + ni * 512);
#pragma unroll
    for (int mi = 0; mi < 4; ++mi)
#pragma unroll
      for (int ni = 0; ni < 4; ++ni)
        acc[mi][ni] = __builtin_amdgcn_mfma_f32_16x16x32_bf16(af[mi], bfr[ni], acc[mi][ni], 0, 0, 0);
#pragma unroll
    for (int i = 0; i < 4; ++i) gp[i] += 32;
  }

#pragma unroll
  for (int ni = 0; ni < 4; ++ni) {
    int Cc = nt * 128 + wn * 64 + ni * 16 + r16;
    if (Cc < 64 * d) {
      int g = Cc / d, v = Cc - (Cc / d) * d;
#pragma unroll
      for (int mi = 0; mi < 4; ++mi) {
        int R0 = mt * 128 + wm * 64 + mi * 16 + q * 4;
#pragma unroll
        for (int reg = 0; reg < 4; ++reg) {
          int R = R0 + reg;
          int bb = R / d, m = R - (R / d) * d;
          out[(size_t)bb * XROW + g * 455 + OFF + v * d + m] = acc[mi][ni][reg];
        }
      }
    }
  }
}

__global__ __launch_bounds__(256) void gemm_all(const unsigned short* __restrict__ ws, float* __restrict__ out) {
  __shared__ alignas(16) unsigned short As[128 * 32];
  __shared__ alignas(16) unsigned short Bs[128 * 32];
  // blocks per l: 4d(d+1) = {8,48,120,224,360,528,728}; cum {8,56,176,400,760,1288,2016}
  int b0 = 2015 - (int)blockIdx.x;   // longest-l blocks dispatch first
  if      (b0 <    8) gemm_body<0>(b0,        ws, out, As, Bs);
  else if (b0 <   56) gemm_body<1>(b0 -    8, ws, out, As, Bs);
  else if (b0 <  176) gemm_body<2>(b0 -   56, ws, out, As, Bs);
  else if (b0 <  400) gemm_body<3>(b0 -  176, ws, out, As, Bs);
  else if (b0 <  760) gemm_body<4>(b0 -  400, ws, out, As, Bs);
  else if (b0 < 1288) gemm_body<5>(b0 -  760, ws, out, As, Bs);
  else                gemm_body<6>(b0 - 1288, ws, out, As, Bs);
}

extern "C" void kernel_launch(void* const* d_in, const int* in_sizes, int n_in,
                              void* d_out, int out_size, void* d_ws, size_t ws_size,
                              hipStream_t stream) {
  const float* x = (const float*)d_in[0];
  const float* D = (const float*)d_in[1];
  const float* w = (const float*)d_in[2];
  float* out = (float*)d_out;
  unsigned short* ws = (unsigned short*)d_ws;   // ~63.8 MB

  hipLaunchKernelGGL(prep, dim3(1472), dim3(256), 0, stream, x, D, w, ws);
  hipLaunchKernelGGL(gemm_all, dim3(2016), dim3(256), 0, stream, ws, out);
}